// Round 1
// baseline (299.789 us; speedup 1.0000x reference)
//
#include <hip/hip_runtime.h>
#include <hip/hip_fp16.h>
#include <math.h>

#define N_NODES 100000
#define N_EDGES 1250000
#define D 64
#define EPS 1e-8f

// ---------------------------------------------------------------------------
// Kernel 1: hn[i,:] = normalize(tanh(x[i,:] @ W^T + b)) -> fp16
// ---------------------------------------------------------------------------
__global__ __launch_bounds__(256) void k_gemm_norm(
    const float* __restrict__ x, const float* __restrict__ W,
    const float* __restrict__ b, __half* __restrict__ hn)
{
    __shared__ float xrow[4][72];
    const int lane = threadIdx.x & 63;
    const int wid  = threadIdx.x >> 6;

    float Wreg[64];
    const float4* Wv = (const float4*)(W + lane * D);
    #pragma unroll
    for (int q = 0; q < 16; ++q) {
        float4 w4 = Wv[q];
        Wreg[4*q+0] = w4.x; Wreg[4*q+1] = w4.y;
        Wreg[4*q+2] = w4.z; Wreg[4*q+3] = w4.w;
    }
    const float bj = b[lane];
    float* xl = xrow[wid];

    const int wave   = blockIdx.x * 4 + wid;
    const int nwaves = gridDim.x * 4;

    for (int row = wave; row < N_NODES; row += nwaves) {
        float xv = x[(size_t)row * D + lane];
        xl[lane] = xv;
        float acc = bj;
        #pragma unroll
        for (int q = 0; q < 16; ++q) {
            float4 xk4 = *(const float4*)(xl + 4*q);
            acc = fmaf(xk4.x, Wreg[4*q+0], acc);
            acc = fmaf(xk4.y, Wreg[4*q+1], acc);
            acc = fmaf(xk4.z, Wreg[4*q+2], acc);
            acc = fmaf(xk4.w, Wreg[4*q+3], acc);
        }
        float h = tanhf(acc);
        float s = h * h;
        #pragma unroll
        for (int m = 32; m >= 1; m >>= 1) s += __shfl_xor(s, m, 64);
        float nrm = fmaxf(sqrtf(s), EPS);
        hn[(size_t)row * D + lane] = __float2half_rn(h / nrm);
    }
}

__global__ void k_zero(int* __restrict__ cnt)
{
    int i = blockIdx.x * 256 + threadIdx.x;
    if (i < N_NODES) cnt[i] = 0;
}

// ---------------------------------------------------------------------------
// The ONLY atomic pass: per-edge rank within its destination node.
// ---------------------------------------------------------------------------
__global__ void k_rank(const int* __restrict__ ei, int* __restrict__ cnt,
                       int* __restrict__ rank)
{
    int e = blockIdx.x * 256 + threadIdx.x;
    if (e >= N_EDGES) return;
    int d = ei[N_EDGES + e];
    rank[e] = atomicAdd(cnt + d, 1);
}

// ---------------------------------------------------------------------------
// Scan: exclusive prefix sum of cnt[100000] -> rowptr
// ---------------------------------------------------------------------------
__device__ __forceinline__ int wave_iscan(int v, int lane)
{
    int incl = v;
    #pragma unroll
    for (int m = 1; m < 64; m <<= 1) {
        int o = __shfl_up(incl, m, 64);
        if (lane >= m) incl += o;
    }
    return incl;
}

__global__ __launch_bounds__(256) void k_scan1(
    const int* __restrict__ cnt, int* __restrict__ rowptr, int* __restrict__ bsum)
{
    __shared__ int wsum[4];
    int t = threadIdx.x, b = blockIdx.x;
    int i = b * 256 + t;
    int lane = t & 63, wid = t >> 6;
    int v = (i < N_NODES) ? cnt[i] : 0;
    int incl = wave_iscan(v, lane);
    if (lane == 63) wsum[wid] = incl;
    __syncthreads();
    int off = 0;
    #pragma unroll
    for (int k = 0; k < 4; ++k) if (k < wid) off += wsum[k];
    if (i < N_NODES) rowptr[i] = off + incl - v;
    if (t == 255) bsum[b] = off + incl;
}

__global__ __launch_bounds__(512) void k_scan2(
    const int* __restrict__ bsum, int* __restrict__ boff, int nblk)
{
    __shared__ int wsum[8];
    int t = threadIdx.x;
    int lane = t & 63, wid = t >> 6;
    int v = (t < nblk) ? bsum[t] : 0;
    int incl = wave_iscan(v, lane);
    if (lane == 63) wsum[wid] = incl;
    __syncthreads();
    int off = 0;
    #pragma unroll
    for (int k = 0; k < 8; ++k) if (k < wid) off += wsum[k];
    if (t < nblk) boff[t] = off + incl - v;
}

__global__ __launch_bounds__(256) void k_scan3(
    int* __restrict__ rowptr, const int* __restrict__ boff)
{
    int i = blockIdx.x * 256 + threadIdx.x;
    if (i < N_NODES) rowptr[i] += boff[i >> 8];
    if (i == 0) rowptr[N_NODES] = N_EDGES;
}

// ---------------------------------------------------------------------------
// Pure CSR placement (no cosine, no row gathers). ZERO atomics.
// pairs[pos].x = src ;  rank[e] <- pos   (in-place: read rank before write)
// ---------------------------------------------------------------------------
__global__ __launch_bounds__(256) void k_place(
    const int* __restrict__ ei, int* rank_pos,
    const int* __restrict__ rowptr, int2* __restrict__ pairs)
{
    int e = blockIdx.x * 256 + threadIdx.x;
    if (e >= N_EDGES) return;
    int s = ei[e];
    int d = ei[N_EDGES + e];
    int pos = rowptr[d] + rank_pos[e];
    pairs[pos] = make_int2(s, 0);
    rank_pos[e] = pos;          // edge -> CSR slot, for k_wout
}

// ---------------------------------------------------------------------------
// Fused cosine + degree + dis + y0. One wave per node, 8 lanes per edge,
// 8 edges in flight. Dst row loaded ONCE per node (registers) -> only the
// src row gather is random. Writes w into pairs[j].y (near-sequential).
// ---------------------------------------------------------------------------
__device__ __forceinline__ float dot8h(float4 a, float4 c)
{
    const __half2* ah = (const __half2*)&a;
    const __half2* ch = (const __half2*)&c;
    float p = 0.0f;
    #pragma unroll
    for (int q = 0; q < 4; ++q) {
        float2 af = __half22float2(ah[q]);
        float2 cf = __half22float2(ch[q]);
        p = fmaf(af.x, cf.x, p);
        p = fmaf(af.y, cf.y, p);
    }
    return p;
}

__global__ __launch_bounds__(256) void k_cos_deg_y(
    const __half* __restrict__ hn, const int* __restrict__ rowptr,
    int2* __restrict__ pairs, const float* __restrict__ mask,
    float* __restrict__ dis, float* __restrict__ y)
{
    const int node = blockIdx.x * 4 + (threadIdx.x >> 6);
    if (node >= N_NODES) return;
    const int lane = threadIdx.x & 63;
    const int sub  = lane & 7;    // chunk of the row (8 halves each)
    const int g    = lane >> 3;   // edge group 0..7

    // own (dst) row fragment, loaded once
    const float4 c = ((const float4*)(hn + (size_t)node * D))[sub];

    const int beg = rowptr[node], end = rowptr[node + 1];
    float s = 0.0f;
    for (int j0 = beg; j0 < end; j0 += 8) {
        int j = j0 + g;
        if (j < end) {                      // uniform within the 8-lane group
            int src = ((const int*)pairs)[2 * j];     // .x
            float4 a = ((const float4*)(hn + (size_t)src * D))[sub];
            float p = dot8h(a, c);
            p += __shfl_xor(p, 1, 64);
            p += __shfl_xor(p, 2, 64);
            p += __shfl_xor(p, 4, 64);
            if (sub == 0) {
                float w = fmaxf(p, 0.0f);
                ((int*)pairs)[2 * j + 1] = __float_as_int(w);   // .y = w
                s += w;
            }
        }
    }
    // reduce the per-group partial degrees (live on sub==0 lanes, others 0)
    s += __shfl_xor(s, 8, 64);
    s += __shfl_xor(s, 16, 64);
    s += __shfl_xor(s, 32, 64);
    if (lane == 0) {
        float di = rsqrtf(fmaxf(s + 1.0f, EPS));   // +1 self-loop
        dis[node] = di;
        y[node] = di * fmaxf(mask[node], 0.0f);
    }
}

// ---------------------------------------------------------------------------
// wout[e] = pairs[pos[e]].y  — sequential pos read, 4B gather from the
// L3-resident pairs array, coalesced write. No scatter/RMW amplification.
// ---------------------------------------------------------------------------
__global__ __launch_bounds__(256) void k_wout(
    const int* __restrict__ pos, const int2* __restrict__ pairs,
    float* __restrict__ wout)
{
    int e = blockIdx.x * 256 + threadIdx.x;
    if (e >= N_EDGES) return;
    wout[e] = __int_as_float(((const int*)pairs)[2 * pos[e] + 1]);
}

// ---------------------------------------------------------------------------
// APPNP step in y-domain, 16 lanes per node, no atomics:
// f'_i = (1-a) * dis_i * ( sum_j w_ij*y_j + y_i ) + a*relu(mask_i)
// y'_i = dis_i * f'_i
// ---------------------------------------------------------------------------
__global__ __launch_bounds__(256) void k_spmv(
    const int* __restrict__ rowptr, const int2* __restrict__ pairs,
    const float* __restrict__ y_in, const float* __restrict__ dis,
    const float* __restrict__ mask, const float* __restrict__ alpha_p,
    float* __restrict__ y_out, float* __restrict__ f_out)
{
    int t = blockIdx.x * 256 + threadIdx.x;
    int node = t >> 4, l = t & 15;
    if (node >= N_NODES) return;
    int beg = rowptr[node], end = rowptr[node + 1];
    float sum = 0.0f;
    for (int j = beg + l; j < end; j += 16) {
        int2 p = pairs[j];
        sum += __int_as_float(p.y) * y_in[p.x];
    }
    sum += __shfl_xor(sum, 1, 64);
    sum += __shfl_xor(sum, 2, 64);
    sum += __shfl_xor(sum, 4, 64);
    sum += __shfl_xor(sum, 8, 64);
    if (l == 0) {
        float di = dis[node];
        float alpha = alpha_p[0];
        float f0 = fmaxf(mask[node], 0.0f);
        float fn = (1.0f - alpha) * di * (sum + y_in[node]) + alpha * f0;
        f_out[node] = fn;
        y_out[node] = di * fn;
    }
}

extern "C" void kernel_launch(void* const* d_in, const int* in_sizes, int n_in,
                              void* d_out, int out_size, void* d_ws, size_t ws_size,
                              hipStream_t stream)
{
    const float* x     = (const float*)d_in[0];
    const float* mask  = (const float*)d_in[1];
    const int*   ei    = (const int*)  d_in[2];
    const float* W     = (const float*)d_in[3];
    const float* b     = (const float*)d_in[4];
    const float* alpha = (const float*)d_in[5];

    float* out_f = (float*)d_out;
    float* out_w = (float*)d_out + N_NODES;

    // workspace layout (float-element offsets) — unchanged from baseline
    float* ws = (float*)d_ws;
    __half* hn     = (__half*)ws;                  // 6.4M halves (3.2M floats)
    int2*  pairs   = (int2*) (ws + 3200000);       // 1.25M x 8B
    int*   rank    = (int*)  (ws + 5700000);       // 1.25M (becomes pos[] after k_place)
    int*   cnt     = (int*)  (ws + 6950000);       // 100k
    int*   rowptr  = (int*)  (ws + 7050000);       // 100001 (alloc 100016)
    float* dis     =          ws + 7150016;        // 100k
    float* y_a     =          ws + 7250016;        // 100k
    float* y_b     =          ws + 7350016;        // 100k
    float* f_scr   =          ws + 7450016;        // 100k
    int*   bsum    = (int*)  (ws + 7550016);       // 391 (alloc 512)
    int*   boff    = (int*)  (ws + 7550528);       // 391

    const int nodeBlocks = (N_NODES + 255) / 256;                    // 391
    const int edgeBlocks = (N_EDGES + 255) / 256;                    // 4883
    const int cosBlocks  = N_NODES / 4;                              // 25000 (4 waves/block)
    const int segBlocks  = (int)(((long long)N_NODES * 16 + 255) / 256);  // 6250

    k_zero<<<nodeBlocks, 256, 0, stream>>>(cnt);
    k_rank<<<edgeBlocks, 256, 0, stream>>>(ei, cnt, rank);
    k_gemm_norm<<<1024, 256, 0, stream>>>(x, W, b, hn);
    k_scan1<<<nodeBlocks, 256, 0, stream>>>(cnt, rowptr, bsum);
    k_scan2<<<1, 512, 0, stream>>>(bsum, boff, nodeBlocks);
    k_scan3<<<nodeBlocks, 256, 0, stream>>>(rowptr, boff);
    k_place<<<edgeBlocks, 256, 0, stream>>>(ei, rank, rowptr, pairs);
    k_cos_deg_y<<<cosBlocks, 256, 0, stream>>>(hn, rowptr, pairs, mask, dis, y_a);
    k_wout<<<edgeBlocks, 256, 0, stream>>>(rank, pairs, out_w);

    // 5 APPNP steps in y-domain; last writes f to d_out
    k_spmv<<<segBlocks, 256, 0, stream>>>(rowptr, pairs, y_a, dis, mask, alpha, y_b, f_scr);
    k_spmv<<<segBlocks, 256, 0, stream>>>(rowptr, pairs, y_b, dis, mask, alpha, y_a, f_scr);
    k_spmv<<<segBlocks, 256, 0, stream>>>(rowptr, pairs, y_a, dis, mask, alpha, y_b, f_scr);
    k_spmv<<<segBlocks, 256, 0, stream>>>(rowptr, pairs, y_b, dis, mask, alpha, y_a, f_scr);
    k_spmv<<<segBlocks, 256, 0, stream>>>(rowptr, pairs, y_a, dis, mask, alpha, y_b, out_f);
}

// Round 2
// 282.524 us; speedup vs baseline: 1.0611x; 1.0611x over previous
//
#include <hip/hip_runtime.h>
#include <hip/hip_fp16.h>
#include <math.h>

#define N_NODES 100000
#define N_EDGES 1250000
#define D 64
#define EPS 1e-8f

// ---------------------------------------------------------------------------
// Kernel 1: hn[i,:] = normalize(tanh(x[i,:] @ W^T + b)) -> fp16
// ---------------------------------------------------------------------------
__global__ __launch_bounds__(256) void k_gemm_norm(
    const float* __restrict__ x, const float* __restrict__ W,
    const float* __restrict__ b, __half* __restrict__ hn)
{
    __shared__ float xrow[4][72];
    const int lane = threadIdx.x & 63;
    const int wid  = threadIdx.x >> 6;

    float Wreg[64];
    const float4* Wv = (const float4*)(W + lane * D);
    #pragma unroll
    for (int q = 0; q < 16; ++q) {
        float4 w4 = Wv[q];
        Wreg[4*q+0] = w4.x; Wreg[4*q+1] = w4.y;
        Wreg[4*q+2] = w4.z; Wreg[4*q+3] = w4.w;
    }
    const float bj = b[lane];
    float* xl = xrow[wid];

    const int wave   = blockIdx.x * 4 + wid;
    const int nwaves = gridDim.x * 4;

    for (int row = wave; row < N_NODES; row += nwaves) {
        float xv = x[(size_t)row * D + lane];
        xl[lane] = xv;
        float acc = bj;
        #pragma unroll
        for (int q = 0; q < 16; ++q) {
            float4 xk4 = *(const float4*)(xl + 4*q);
            acc = fmaf(xk4.x, Wreg[4*q+0], acc);
            acc = fmaf(xk4.y, Wreg[4*q+1], acc);
            acc = fmaf(xk4.z, Wreg[4*q+2], acc);
            acc = fmaf(xk4.w, Wreg[4*q+3], acc);
        }
        float h = tanhf(acc);
        float s = h * h;
        #pragma unroll
        for (int m = 32; m >= 1; m >>= 1) s += __shfl_xor(s, m, 64);
        float nrm = fmaxf(sqrtf(s), EPS);
        hn[(size_t)row * D + lane] = __float2half_rn(h / nrm);
    }
}

__global__ void k_zero(int* __restrict__ cnt)
{
    int i = blockIdx.x * 256 + threadIdx.x;
    if (i < N_NODES) cnt[i] = 0;
}

// ---------------------------------------------------------------------------
// The ONLY atomic pass: per-edge rank within its destination node.
// ---------------------------------------------------------------------------
__global__ void k_rank(const int* __restrict__ ei, int* __restrict__ cnt,
                       int* __restrict__ rank)
{
    int e = blockIdx.x * 256 + threadIdx.x;
    if (e >= N_EDGES) return;
    int d = ei[N_EDGES + e];
    rank[e] = atomicAdd(cnt + d, 1);
}

// ---------------------------------------------------------------------------
// Scan: exclusive prefix sum of cnt[100000] -> rowptr
// ---------------------------------------------------------------------------
__device__ __forceinline__ int wave_iscan(int v, int lane)
{
    int incl = v;
    #pragma unroll
    for (int m = 1; m < 64; m <<= 1) {
        int o = __shfl_up(incl, m, 64);
        if (lane >= m) incl += o;
    }
    return incl;
}

__global__ __launch_bounds__(256) void k_scan1(
    const int* __restrict__ cnt, int* __restrict__ rowptr, int* __restrict__ bsum)
{
    __shared__ int wsum[4];
    int t = threadIdx.x, b = blockIdx.x;
    int i = b * 256 + t;
    int lane = t & 63, wid = t >> 6;
    int v = (i < N_NODES) ? cnt[i] : 0;
    int incl = wave_iscan(v, lane);
    if (lane == 63) wsum[wid] = incl;
    __syncthreads();
    int off = 0;
    #pragma unroll
    for (int k = 0; k < 4; ++k) if (k < wid) off += wsum[k];
    if (i < N_NODES) rowptr[i] = off + incl - v;
    if (t == 255) bsum[b] = off + incl;
}

__global__ __launch_bounds__(512) void k_scan2(
    const int* __restrict__ bsum, int* __restrict__ boff, int nblk)
{
    __shared__ int wsum[8];
    int t = threadIdx.x;
    int lane = t & 63, wid = t >> 6;
    int v = (t < nblk) ? bsum[t] : 0;
    int incl = wave_iscan(v, lane);
    if (lane == 63) wsum[wid] = incl;
    __syncthreads();
    int off = 0;
    #pragma unroll
    for (int k = 0; k < 8; ++k) if (k < wid) off += wsum[k];
    if (t < nblk) boff[t] = off + incl - v;
}

__global__ __launch_bounds__(256) void k_scan3(
    int* __restrict__ rowptr, const int* __restrict__ boff)
{
    int i = blockIdx.x * 256 + threadIdx.x;
    if (i < N_NODES) rowptr[i] += boff[i >> 8];
    if (i == 0) rowptr[N_NODES] = N_EDGES;
}

// ---------------------------------------------------------------------------
// Pure CSR placement (no cosine, no row gathers). ZERO atomics.
// pairs[pos] = (src, dst) ;  rank[e] <- pos   (read rank before write)
// ---------------------------------------------------------------------------
__global__ __launch_bounds__(256) void k_place(
    const int* __restrict__ ei, int* rank_pos,
    const int* __restrict__ rowptr, int2* __restrict__ pairs)
{
    int e = blockIdx.x * 256 + threadIdx.x;
    if (e >= N_EDGES) return;
    int s = ei[e];
    int d = ei[N_EDGES + e];
    int pos = rowptr[d] + rank_pos[e];
    pairs[pos] = make_int2(s, d);
    rank_pos[e] = pos;          // edge -> CSR slot, for k_wout
}

// ---------------------------------------------------------------------------
// Cosine in CSR order, EDGE-PARALLEL (8 lanes/edge, 4 edges/group, 8 row
// gathers in flight). Consecutive CSR slots share dst -> dst-row gathers are
// L1/L2 hits; only src gathers are random. Overwrites pairs[j] = (src, w)
// with two coalesced int4 stores.
// ---------------------------------------------------------------------------
__device__ __forceinline__ float dot8h(float4 a, float4 c)
{
    const __half2* ah = (const __half2*)&a;
    const __half2* ch = (const __half2*)&c;
    float p = 0.0f;
    #pragma unroll
    for (int q = 0; q < 4; ++q) {
        float2 af = __half22float2(ah[q]);
        float2 cf = __half22float2(ch[q]);
        p = fmaf(af.x, cf.x, p);
        p = fmaf(af.y, cf.y, p);
    }
    return p;
}

__global__ __launch_bounds__(256) void k_cos(
    const __half* __restrict__ hn, int2* __restrict__ pairs)
{
    int t = blockIdx.x * 256 + threadIdx.x;
    int g = t >> 3, sub = t & 7;
    if (g >= N_EDGES / 4) return;
    int j0 = g * 4;
    int* pw = (int*)pairs;
    int4 lo = *(const int4*)(pw + 2 * j0);      // s0,d0,s1,d1
    int4 hi = *(const int4*)(pw + 2 * j0 + 4);  // s2,d2,s3,d3

    float4 a0 = ((const float4*)(hn + (size_t)lo.x * D))[sub];
    float4 c0 = ((const float4*)(hn + (size_t)lo.y * D))[sub];
    float4 a1 = ((const float4*)(hn + (size_t)lo.z * D))[sub];
    float4 c1 = ((const float4*)(hn + (size_t)lo.w * D))[sub];
    float4 a2 = ((const float4*)(hn + (size_t)hi.x * D))[sub];
    float4 c2 = ((const float4*)(hn + (size_t)hi.y * D))[sub];
    float4 a3 = ((const float4*)(hn + (size_t)hi.z * D))[sub];
    float4 c3 = ((const float4*)(hn + (size_t)hi.w * D))[sub];

    float p0 = dot8h(a0, c0);
    float p1 = dot8h(a1, c1);
    float p2 = dot8h(a2, c2);
    float p3 = dot8h(a3, c3);
    p0 += __shfl_xor(p0, 1, 64);  p1 += __shfl_xor(p1, 1, 64);
    p2 += __shfl_xor(p2, 1, 64);  p3 += __shfl_xor(p3, 1, 64);
    p0 += __shfl_xor(p0, 2, 64);  p1 += __shfl_xor(p1, 2, 64);
    p2 += __shfl_xor(p2, 2, 64);  p3 += __shfl_xor(p3, 2, 64);
    p0 += __shfl_xor(p0, 4, 64);  p1 += __shfl_xor(p1, 4, 64);
    p2 += __shfl_xor(p2, 4, 64);  p3 += __shfl_xor(p3, 4, 64);

    if (sub == 0) {
        int w0 = __float_as_int(fmaxf(p0, 0.0f));
        int w1 = __float_as_int(fmaxf(p1, 0.0f));
        int w2 = __float_as_int(fmaxf(p2, 0.0f));
        int w3 = __float_as_int(fmaxf(p3, 0.0f));
        *(int4*)(pw + 2 * j0)     = make_int4(lo.x, w0, lo.z, w1);
        *(int4*)(pw + 2 * j0 + 4) = make_int4(hi.x, w2, hi.z, w3);
    }
}

// ---------------------------------------------------------------------------
// deg via segment-sum, 16 lanes per node; dis = rsqrt(deg); y0 = dis*relu(mask)
// ---------------------------------------------------------------------------
__global__ __launch_bounds__(256) void k_dis_y(
    const int* __restrict__ rowptr, const int2* __restrict__ pairs,
    const float* __restrict__ mask, float* __restrict__ dis,
    float* __restrict__ y)
{
    int t = blockIdx.x * 256 + threadIdx.x;
    int node = t >> 4, l = t & 15;
    if (node >= N_NODES) return;
    int beg = rowptr[node], end = rowptr[node + 1];
    float s = 0.0f;
    for (int j = beg + l; j < end; j += 16)
        s += __int_as_float(pairs[j].y);
    s += __shfl_xor(s, 1, 64);
    s += __shfl_xor(s, 2, 64);
    s += __shfl_xor(s, 4, 64);
    s += __shfl_xor(s, 8, 64);
    if (l == 0) {
        float di = rsqrtf(fmaxf(s + 1.0f, EPS));   // +1 self-loop
        dis[node] = di;
        y[node] = di * fmaxf(mask[node], 0.0f);
    }
}

// ---------------------------------------------------------------------------
// wout[e] = pairs[pos[e]].y  — sequential pos read, 4B gather from the
// L3-resident pairs array, coalesced write.
// ---------------------------------------------------------------------------
__global__ __launch_bounds__(256) void k_wout(
    const int* __restrict__ pos, const int2* __restrict__ pairs,
    float* __restrict__ wout)
{
    int e = blockIdx.x * 256 + threadIdx.x;
    if (e >= N_EDGES) return;
    wout[e] = __int_as_float(((const int*)pairs)[2 * pos[e] + 1]);
}

// ---------------------------------------------------------------------------
// APPNP step in y-domain, 16 lanes per node, no atomics:
// f'_i = (1-a) * dis_i * ( sum_j w_ij*y_j + y_i ) + a*relu(mask_i)
// y'_i = dis_i * f'_i
// ---------------------------------------------------------------------------
__global__ __launch_bounds__(256) void k_spmv(
    const int* __restrict__ rowptr, const int2* __restrict__ pairs,
    const float* __restrict__ y_in, const float* __restrict__ dis,
    const float* __restrict__ mask, const float* __restrict__ alpha_p,
    float* __restrict__ y_out, float* __restrict__ f_out)
{
    int t = blockIdx.x * 256 + threadIdx.x;
    int node = t >> 4, l = t & 15;
    if (node >= N_NODES) return;
    int beg = rowptr[node], end = rowptr[node + 1];
    float sum = 0.0f;
    for (int j = beg + l; j < end; j += 16) {
        int2 p = pairs[j];
        sum += __int_as_float(p.y) * y_in[p.x];
    }
    sum += __shfl_xor(sum, 1, 64);
    sum += __shfl_xor(sum, 2, 64);
    sum += __shfl_xor(sum, 4, 64);
    sum += __shfl_xor(sum, 8, 64);
    if (l == 0) {
        float di = dis[node];
        float alpha = alpha_p[0];
        float f0 = fmaxf(mask[node], 0.0f);
        float fn = (1.0f - alpha) * di * (sum + y_in[node]) + alpha * f0;
        f_out[node] = fn;
        y_out[node] = di * fn;
    }
}

extern "C" void kernel_launch(void* const* d_in, const int* in_sizes, int n_in,
                              void* d_out, int out_size, void* d_ws, size_t ws_size,
                              hipStream_t stream)
{
    const float* x     = (const float*)d_in[0];
    const float* mask  = (const float*)d_in[1];
    const int*   ei    = (const int*)  d_in[2];
    const float* W     = (const float*)d_in[3];
    const float* b     = (const float*)d_in[4];
    const float* alpha = (const float*)d_in[5];

    float* out_f = (float*)d_out;
    float* out_w = (float*)d_out + N_NODES;

    // workspace layout (float-element offsets)
    float* ws = (float*)d_ws;
    __half* hn     = (__half*)ws;                  // 6.4M halves (3.2M floats)
    int2*  pairs   = (int2*) (ws + 3200000);       // 1.25M x 8B
    int*   rank    = (int*)  (ws + 5700000);       // 1.25M (becomes pos[] after k_place)
    int*   cnt     = (int*)  (ws + 6950000);       // 100k
    int*   rowptr  = (int*)  (ws + 7050000);       // 100001 (alloc 100016)
    float* dis     =          ws + 7150016;        // 100k
    float* y_a     =          ws + 7250016;        // 100k
    float* y_b     =          ws + 7350016;        // 100k
    float* f_scr   =          ws + 7450016;        // 100k
    int*   bsum    = (int*)  (ws + 7550016);       // 391 (alloc 512)
    int*   boff    = (int*)  (ws + 7550528);       // 391

    const int nodeBlocks = (N_NODES + 255) / 256;                         // 391
    const int edgeBlocks = (N_EDGES + 255) / 256;                         // 4883
    const int cosBlocks  = (int)(((long long)(N_EDGES / 4) * 8 + 255) / 256); // 9766
    const int segBlocks  = (int)(((long long)N_NODES * 16 + 255) / 256);      // 6250

    k_zero<<<nodeBlocks, 256, 0, stream>>>(cnt);
    k_rank<<<edgeBlocks, 256, 0, stream>>>(ei, cnt, rank);
    k_gemm_norm<<<1024, 256, 0, stream>>>(x, W, b, hn);
    k_scan1<<<nodeBlocks, 256, 0, stream>>>(cnt, rowptr, bsum);
    k_scan2<<<1, 512, 0, stream>>>(bsum, boff, nodeBlocks);
    k_scan3<<<nodeBlocks, 256, 0, stream>>>(rowptr, boff);
    k_place<<<edgeBlocks, 256, 0, stream>>>(ei, rank, rowptr, pairs);
    k_cos<<<cosBlocks, 256, 0, stream>>>(hn, pairs);
    k_dis_y<<<segBlocks, 256, 0, stream>>>(rowptr, pairs, mask, dis, y_a);
    k_wout<<<edgeBlocks, 256, 0, stream>>>(rank, pairs, out_w);

    // 5 APPNP steps in y-domain; last writes f to d_out
    k_spmv<<<segBlocks, 256, 0, stream>>>(rowptr, pairs, y_a, dis, mask, alpha, y_b, f_scr);
    k_spmv<<<segBlocks, 256, 0, stream>>>(rowptr, pairs, y_b, dis, mask, alpha, y_a, f_scr);
    k_spmv<<<segBlocks, 256, 0, stream>>>(rowptr, pairs, y_a, dis, mask, alpha, y_b, f_scr);
    k_spmv<<<segBlocks, 256, 0, stream>>>(rowptr, pairs, y_b, dis, mask, alpha, y_a, f_scr);
    k_spmv<<<segBlocks, 256, 0, stream>>>(rowptr, pairs, y_a, dis, mask, alpha, y_b, out_f);
}